// Round 15
// baseline (251.516 us; speedup 1.0000x reference)
//
#include <hip/hip_runtime.h>
#include <hip/hip_bf16.h>
#include <math.h>

typedef __attribute__((ext_vector_type(4))) float  f32x4;
typedef __attribute__((ext_vector_type(8))) __bf16 bf16x8;
typedef __attribute__((ext_vector_type(4))) unsigned int u32x4;

__device__ __forceinline__ f32x4 MF(bf16x8 a, bf16x8 b, f32x4 c) {
    return __builtin_amdgcn_mfma_f32_16x16x32_bf16(a, b, c, 0, 0, 0);
}

__device__ __forceinline__ f32x4 zero4() { f32x4 z = {0.f, 0.f, 0.f, 0.f}; return z; }

// packed f32->bf16 (RNE), 2 elems/instr
__device__ __forceinline__ unsigned int pkbf(float lo, float hi) {
    unsigned int r;
    asm("v_cvt_pk_bf16_f32 %0, %1, %2" : "=v"(r) : "v"(lo), "v"(hi));
    return r;
}
__device__ __forceinline__ unsigned long long pk4(f32x4 x) {
    return (unsigned long long)pkbf(x[0], x[1]) | ((unsigned long long)pkbf(x[2], x[3]) << 32);
}

// B-fragment (BT row-major, contiguous K): lane holds BT[row][k0..k0+7], f32 -> bf16
__device__ __forceinline__ bf16x8 bfrag_g(const float* W, int ldk, int row, int k0) {
    const float* p = W + (size_t)row * ldk + k0;
    bf16x8 r;
#pragma unroll
    for (int e = 0; e < 8; ++e) r[e] = (__bf16)p[e];
    return r;
}

// ---- LDS layout (bytes): padded rows + additive rotate swizzle ----
#define VSET     18432                  // 3 * 16 * 384
#define SET_SZ   28672                  // VSET + 16*640
#define S1_OFF   57344                  // 16*384
#define RED_OFF  63488                  // 8 waves * 16 f32 = 512
#define SVAL_OFF 64000                  // 16 f32 (this tile's s values)
#define YL_OFF   64064                  // 256 f32 per-molecule partials
#define LDS_BYTES 65088

// 16B LDS read at precomputed lane pointer + compile-time byte immediate
__device__ __forceinline__ bf16x8 ld16(const unsigned char* p, int imm) {
    return __builtin_bit_cast(bf16x8, *(const u32x4*)(p + imm));
}

__global__ __launch_bounds__(512, 2) void eqsc_main(
    const float* __restrict__ S, const float* __restrict__ V,
    const float* __restrict__ batch,
    const float* __restrict__ u0w, const float* __restrict__ v0w,
    const float* __restrict__ a0w1, const float* __restrict__ a0b1,
    const float* __restrict__ a0w2, const float* __restrict__ a0b2,
    const float* __restrict__ v1w,
    const float* __restrict__ a1w1, const float* __restrict__ a1b1,
    const float* __restrict__ a1w2,  const float* __restrict__ a1b2,
    const float* __restrict__ outw, const float* __restrict__ outbp,
    float* __restrict__ Y, int NT, int NA, int B)
{
    __shared__ __align__(16) unsigned char lds[LDS_BYTES];
    const int tid  = threadIdx.x;
    const int lane = tid & 63;
    const int wv   = tid >> 6;
    const int l15  = lane & 15;
    const int lg   = lane >> 4;
    const int grow = wv * 16 + l15;
    const int fb0  = wv * 16 + (lg << 2);

    // lane-invariant address pieces
    const int lgsw    = (lg + (l15 & 7)) << 4;
    const int lrow384 = l15 * 384 + lgsw;
    const int lrow640 = l15 * 640 + lgsw;
    const int erot    = (fb0 << 1) + ((l15 & 7) << 4);
    const int eoffV   = l15 * 384 + erot;
    const int eoffH   = l15 * 640 + erot;

    int vstoff[3], sstoff;
#pragma unroll
    for (int j = 0; j < 3; ++j) {
        int c = tid + (j << 9);
        int d = c >> 9, rem = c & 511;
        int row = rem >> 5, c4 = rem & 31;
        vstoff[j] = d * 6144 + row * 384 + (c4 << 3) + ((row & 7) << 4);
    }
    { int row = tid >> 5, c4 = tid & 31;
      sstoff = row * 640 + (c4 << 3) + ((row & 7) << 4); }

    // ---- folded readout (vector) ----
    f32x4 wfv = zero4();
    float cf = 0.f;
    for (int g = 0; g < 128; ++g) {
        float og = outw[g];
        f32x4 w4 = *(const f32x4*)(a1w2 + g * 128 + fb0);
#pragma unroll
        for (int e = 0; e < 4; ++e) wfv[e] += w4[e] * og;
        cf += a1b2[g] * og;
    }
    cf += outbp[0];

    // ---- persistent weight fragments (bf16): 144 regs ----
    bf16x8 uw0f[4], vw0f[4], w2g0[4], w2s0[4], vw1f[4];
    bf16x8 w1f0[8], w1f1[8];
#pragma unroll
    for (int kt = 0; kt < 4; ++kt) {
        int k0 = kt * 32 + lg * 8;
        uw0f[kt] = bfrag_g(u0w, 128, grow, k0);
        vw0f[kt] = bfrag_g(v0w, 128, grow, k0);
        w2g0[kt] = bfrag_g(a0w2, 128, grow, k0);
        w2s0[kt] = bfrag_g(a0w2, 128, 128 + grow, k0);
        vw1f[kt] = bfrag_g(v1w, 128, grow, k0);
    }
#pragma unroll
    for (int kt = 0; kt < 8; ++kt) {
        int k0 = kt * 32 + lg * 8;
        w1f0[kt] = bfrag_g(a0w1, 256, grow, k0);
        w1f1[kt] = bfrag_g(a1w1, 256, grow, k0);
    }
    const f32x4 b1_0v = *(const f32x4*)(a0b1 + fb0);
    const f32x4 b2g0v = *(const f32x4*)(a0b2 + fb0);
    const f32x4 b2s0v = *(const f32x4*)(a0b2 + 128 + fb0);
    const f32x4 b1_1v = *(const f32x4*)(a1b1 + fb0);

    const int stride = gridDim.x;
    const int t0 = blockIdx.x;
    const int NI = (NT - t0 + stride - 1) / stride;   // t0 < NT for this launch

    // fused-pool state
    float* yl = (float*)(lds + YL_OFF);
    float* sv = (float*)(lds + SVAL_OFF);
    const int pb   = tid >> 1;            // molecule this thread accumulates
    const int palo = (tid & 1) << 3;      // atom offset within tile (0 or 8)
    f32x4 bb0, bb1;                       // batch regs, loaded slot2, used next slot1

    // ---- prologue: stage tile t0 into set 0 ; zero y partials ----
    {
        f32x4 vld[3], sld;
#pragma unroll
        for (int j = 0; j < 3; ++j) {
            int c = tid + (j << 9);
            int d = c >> 9, rem = c & 511;
            int row = rem >> 5, c4 = rem & 31;
            vld[j] = *(const f32x4*)(V + (((size_t)((t0 << 4) + row) * 3 + d) << 7) + (c4 << 2));
        }
        { int row = tid >> 5, c4 = tid & 31;
          sld = *(const f32x4*)(S + (((size_t)((t0 << 4) + row)) << 7) + (c4 << 2)); }
#pragma unroll
        for (int j = 0; j < 3; ++j)
            *(unsigned long long*)(lds + vstoff[j]) = pk4(vld[j]);
        *(unsigned long long*)(lds + VSET + sstoff) = pk4(sld);
        if (tid < 256) yl[tid] = 0.f;
    }
    __syncthreads();

    for (int i = 0; i < NI + 2; ++i) {
        const int  ty = t0 + i * stride;
        const bool yv = (i < NI);
        const bool xv = (i >= 1) && (i - 1 < NI);
        const bool cv = (i >= 2) && (i - 2 < NI);
        const bool zv = (i + 1 < NI);
        const int  tz = ty + stride;
        unsigned char* baseY = lds + (i & 1) * SET_SZ;
        unsigned char* baseX = lds + ((i & 1) ^ 1) * SET_SZ;
        const unsigned char* pVY = baseY + lrow384;
        const unsigned char* pHY = baseY + VSET + lrow640;
        const unsigned char* pVX = baseX + lrow384;
        const unsigned char* pHX = baseX + VSET + lrow640;
        const unsigned char* pS1 = lds + S1_OFF + lrow384;

        // ======== slot 1: issue Z loads ; fused-pool consume (tile i-2) ; Y.P1 || X.P4 ========
        f32x4 vld[3], sld;
        if (zv) {
#pragma unroll
            for (int j = 0; j < 3; ++j) {
                int c = tid + (j << 9);
                int d = c >> 9, rem = c & 511;
                int row = rem >> 5, c4 = rem & 31;
                vld[j] = *(const f32x4*)(V + (((size_t)((tz << 4) + row) * 3 + d) << 7) + (c4 << 2));
            }
            { int row = tid >> 5, c4 = tid & 31;
              sld = *(const f32x4*)(S + (((size_t)((tz << 4) + row)) << 7) + (c4 << 2)); }
        }
        if (cv) {                               // y_lds[b] += batch[b, tile(i-2)] . sVal
            float p = 0.f;
#pragma unroll
            for (int k = 0; k < 4; ++k) p += bb0[k] * sv[palo + k];
#pragma unroll
            for (int k = 0; k < 4; ++k) p += bb1[k] * sv[palo + 4 + k];
            p += __shfl_xor(p, 1);
            if (!(tid & 1)) yl[pb] += p;        // single writer per b
        }

        f32x4 v1a[3];
        if (yv) {
            f32x4 n2 = zero4();
#pragma unroll
            for (int d = 0; d < 3; ++d) {
                f32x4 a1 = zero4(), a2 = zero4();
#pragma unroll
                for (int kt = 0; kt < 4; ++kt) {
                    bf16x8 a = ld16(pVY, d * 6144 + kt * 64);
                    a1 = MF(uw0f[kt], a, a1);
                    a2 = MF(vw0f[kt], a, a2);
                }
                v1a[d] = a1;
#pragma unroll
                for (int e = 0; e < 4; ++e) { float x = a2[e] + 1e-8f; n2[e] += x * x; }
            }
            f32x4 nr;
#pragma unroll
            for (int e = 0; e < 4; ++e) nr[e] = sqrtf(n2[e]);
            *(unsigned long long*)(baseY + VSET + eoffH + 256) = pk4(nr);
        }
        if (xv) {
            f32x4 n2 = zero4();
#pragma unroll
            for (int d = 0; d < 3; ++d) {
                f32x4 acc = zero4();
#pragma unroll
                for (int kt = 0; kt < 4; ++kt)
                    acc = MF(vw1f[kt], ld16(pVX, d * 6144 + kt * 64), acc);
#pragma unroll
                for (int e = 0; e < 4; ++e) { float x = acc[e] + 1e-8f; n2[e] += x * x; }
            }
            f32x4 nr;
#pragma unroll
            for (int e = 0; e < 4; ++e) nr[e] = sqrtf(n2[e]);
            *(unsigned long long*)(baseX + VSET + eoffH + 256) = pk4(nr);
        }
        __syncthreads();

        // ======== slot 2: Y.P2 || X.P5 (readout) ; batch-load (tile i-1) ; write V(Z) ========
        if (xv) {                               // issue batch loads early (L3/HBM latency)
            const float* bp = batch + (size_t)pb * NA + (((size_t)(ty - stride)) << 4) + palo;
            bb0 = *(const f32x4*)bp;
            bb1 = *(const f32x4*)(bp + 4);
        }
        if (yv) {
            f32x4 m = zero4();
#pragma unroll
            for (int kt = 0; kt < 8; ++kt)
                m = MF(w1f0[kt], ld16(pHY, kt * 64), m);
            f32x4 y;
#pragma unroll
            for (int e = 0; e < 4; ++e) {
                float x = m[e] + b1_0v[e];
                y[e] = x / (1.f + __expf(-x));
            }
            *(unsigned long long*)(lds + S1_OFF + eoffV) = pk4(y);
        }
        if (xv) {
            f32x4 m = zero4();
#pragma unroll
            for (int kt = 0; kt < 8; ++kt)
                m = MF(w1f1[kt], ld16(pHX, kt * 64), m);
            float p = 0.f;
#pragma unroll
            for (int e = 0; e < 4; ++e) {
                float x = m[e] + b1_1v[e];
                p += (x / (1.f + __expf(-x))) * wfv[e];
            }
            p += __shfl_xor(p, 16);
            p += __shfl_xor(p, 32);
            if (lane < 16)
                *((float*)(lds + RED_OFF) + (wv << 4) + lane) = p;
        }
        if (zv) {
#pragma unroll
            for (int j = 0; j < 3; ++j)
                *(unsigned long long*)(baseX + vstoff[j]) = pk4(vld[j]);
        }
        __syncthreads();

        // ======== slot 3: Y.P3 ; write S(Z) ; sVal(X) ========
        if (yv) {
            f32x4 sg = zero4(), ssa = zero4();
#pragma unroll
            for (int kt = 0; kt < 4; ++kt) {
                bf16x8 a = ld16(pS1, kt * 64);
                sg  = MF(w2g0[kt], a, sg);
                ssa = MF(w2s0[kt], a, ssa);
            }
            f32x4 g, ssv;
#pragma unroll
            for (int e = 0; e < 4; ++e) {
                g[e]   = sg[e] + b2g0v[e];
                ssv[e] = ssa[e] + b2s0v[e];
            }
            *(unsigned long long*)(baseY + VSET + eoffH) = pk4(g);
#pragma unroll
            for (int d = 0; d < 3; ++d) {
                f32x4 vp;
#pragma unroll
                for (int e = 0; e < 4; ++e) vp[e] = v1a[d][e] * ssv[e];
                *(unsigned long long*)(baseY + d * 6144 + eoffV) = pk4(vp);
            }
        }
        if (zv)
            *(unsigned long long*)(baseX + VSET + sstoff) = pk4(sld);
        if (xv && tid < 16) {                   // s values of tile i-1 -> sVal
            float s = 0.f;
#pragma unroll
            for (int w = 0; w < 8; ++w) s += *((float*)(lds + RED_OFF) + (w << 4) + tid);
            sv[tid] = s + cf;
        }
        __syncthreads();
    }

    // ---- epilogue: one atomicAdd per molecule per block ----
    if (tid < B) atomicAdd(&Y[tid], yl[tid]);
}

extern "C" void kernel_launch(void* const* d_in, const int* in_sizes, int n_in,
                              void* d_out, int out_size, void* d_ws, size_t ws_size,
                              hipStream_t stream)
{
    const float* S     = (const float*)d_in[0];
    const float* V     = (const float*)d_in[1];
    // d_in[2] = pos, unused by the reference
    const float* batch = (const float*)d_in[3];
    const float* u0w   = (const float*)d_in[4];
    const float* v0w   = (const float*)d_in[5];
    const float* a0w1  = (const float*)d_in[6];
    const float* a0b1  = (const float*)d_in[7];
    const float* a0w2  = (const float*)d_in[8];
    const float* a0b2  = (const float*)d_in[9];
    // d_in[10] = u1w (dead code: layer-1 v1 unused by the reference output)
    const float* v1w   = (const float*)d_in[11];
    const float* a1w1  = (const float*)d_in[12];
    const float* a1b1  = (const float*)d_in[13];
    const float* a1w2  = (const float*)d_in[14];
    const float* a1b2  = (const float*)d_in[15];
    const float* outw  = (const float*)d_in[16];
    const float* outb  = (const float*)d_in[17];

    const int NA = in_sizes[0] / 128;
    const int NT = NA / 16;                  // 16 atoms per tile
    const int B  = in_sizes[3] / NA;

    hipMemsetAsync(d_out, 0, (size_t)out_size * sizeof(float), stream);

    eqsc_main<<<256, 512, 0, stream>>>(S, V, batch, u0w, v0w, a0w1, a0b1, a0w2, a0b2,
                                       v1w, a1w1, a1b1, a1w2, a1b2,
                                       outw, outb, (float*)d_out, NT, NA, B);
}

// Round 16
// 244.154 us; speedup vs baseline: 1.0302x; 1.0302x over previous
//
#include <hip/hip_runtime.h>
#include <hip/hip_bf16.h>
#include <math.h>

typedef __attribute__((ext_vector_type(4))) float  f32x4;
typedef __attribute__((ext_vector_type(8))) __bf16 bf16x8;
typedef __attribute__((ext_vector_type(4))) unsigned int u32x4;

__device__ __forceinline__ f32x4 MF(bf16x8 a, bf16x8 b, f32x4 c) {
    return __builtin_amdgcn_mfma_f32_16x16x32_bf16(a, b, c, 0, 0, 0);
}

__device__ __forceinline__ f32x4 zero4() { f32x4 z = {0.f, 0.f, 0.f, 0.f}; return z; }

// packed f32->bf16 (RNE), 2 elems/instr
__device__ __forceinline__ unsigned int pkbf(float lo, float hi) {
    unsigned int r;
    asm("v_cvt_pk_bf16_f32 %0, %1, %2" : "=v"(r) : "v"(lo), "v"(hi));
    return r;
}
__device__ __forceinline__ unsigned long long pk4(f32x4 x) {
    return (unsigned long long)pkbf(x[0], x[1]) | ((unsigned long long)pkbf(x[2], x[3]) << 32);
}

// B-fragment (BT row-major, contiguous K): lane holds BT[row][k0..k0+7], f32 -> bf16
__device__ __forceinline__ bf16x8 bfrag_g(const float* W, int ldk, int row, int k0) {
    const float* p = W + (size_t)row * ldk + k0;
    bf16x8 r;
#pragma unroll
    for (int e = 0; e < 8; ++e) r[e] = (__bf16)p[e];
    return r;
}

// ---- LDS layout (bytes): padded rows + additive rotate swizzle ----
#define VSET     18432                  // 3 * 16 * 384
#define SET_SZ   28672                  // VSET + 16*640
#define S1_OFF   57344                  // 16*384
#define RED_OFF  63488                  // 8 waves * 16 f32
#define LDS_BYTES 64000

// 16B LDS read at precomputed lane pointer + compile-time byte immediate
__device__ __forceinline__ bf16x8 ld16(const unsigned char* p, int imm) {
    return __builtin_bit_cast(bf16x8, *(const u32x4*)(p + imm));
}

// One pipeline iteration. YV/XV/ZV may be compile-time constants (steady loop)
// or runtime bools (boundary iterations). Dataflow identical to verified R14.
#define EQ_ITER(I, YV, XV, ZV)                                                  \
{                                                                               \
    const int  ty_ = t0 + (I) * stride;                                         \
    const int  tz_ = ty_ + stride;                                              \
    unsigned char* baseY = lds + ((I) & 1) * SET_SZ;                            \
    unsigned char* baseX = lds + (((I) & 1) ^ 1) * SET_SZ;                      \
    const unsigned char* pVY = baseY + lrow384;                                 \
    const unsigned char* pHY = baseY + VSET + lrow640;                          \
    const unsigned char* pVX = baseX + lrow384;                                 \
    const unsigned char* pHX = baseX + VSET + lrow640;                          \
    const unsigned char* pS1 = lds + S1_OFF + lrow384;                          \
    f32x4 vld[3], sld;                                                          \
    if (ZV) {                                                                   \
        _Pragma("unroll")                                                       \
        for (int j = 0; j < 3; ++j) {                                           \
            int c = tid + (j << 9);                                             \
            int d = c >> 9, rem = c & 511;                                      \
            int row = rem >> 5, c4 = rem & 31;                                  \
            vld[j] = *(const f32x4*)(V + (((size_t)((tz_ << 4) + row) * 3 + d) << 7) + (c4 << 2)); \
        }                                                                       \
        { int row = tid >> 5, c4 = tid & 31;                                    \
          sld = *(const f32x4*)(S + (((size_t)((tz_ << 4) + row)) << 7) + (c4 << 2)); } \
    }                                                                           \
    f32x4 v1a[3];                                                               \
    if (YV) {                                                                   \
        f32x4 n2 = zero4();                                                     \
        _Pragma("unroll")                                                       \
        for (int d = 0; d < 3; ++d) {                                           \
            f32x4 a1 = zero4(), a2 = zero4();                                   \
            _Pragma("unroll")                                                   \
            for (int kt = 0; kt < 4; ++kt) {                                    \
                bf16x8 a = ld16(pVY, d * 6144 + kt * 64);                       \
                a1 = MF(uw0f[kt], a, a1);                                       \
                a2 = MF(vw0f[kt], a, a2);                                       \
            }                                                                   \
            v1a[d] = a1;                                                        \
            _Pragma("unroll")                                                   \
            for (int e = 0; e < 4; ++e) { float x = a2[e] + 1e-8f; n2[e] += x * x; } \
        }                                                                       \
        f32x4 nr;                                                               \
        _Pragma("unroll")                                                       \
        for (int e = 0; e < 4; ++e) nr[e] = sqrtf(n2[e]);                       \
        *(unsigned long long*)(baseY + VSET + eoffH + 256) = pk4(nr);           \
    }                                                                           \
    if (XV) {                                                                   \
        f32x4 n2 = zero4();                                                     \
        _Pragma("unroll")                                                       \
        for (int d = 0; d < 3; ++d) {                                           \
            f32x4 acc = zero4();                                                \
            _Pragma("unroll")                                                   \
            for (int kt = 0; kt < 4; ++kt)                                      \
                acc = MF(vw1f[kt], ld16(pVX, d * 6144 + kt * 64), acc);         \
            _Pragma("unroll")                                                   \
            for (int e = 0; e < 4; ++e) { float x = acc[e] + 1e-8f; n2[e] += x * x; } \
        }                                                                       \
        f32x4 nr;                                                               \
        _Pragma("unroll")                                                       \
        for (int e = 0; e < 4; ++e) nr[e] = sqrtf(n2[e]);                       \
        *(unsigned long long*)(baseX + VSET + eoffH + 256) = pk4(nr);           \
    }                                                                           \
    __syncthreads();                                                            \
    if (YV) {                                                                   \
        f32x4 m = zero4();                                                      \
        _Pragma("unroll")                                                       \
        for (int kt = 0; kt < 8; ++kt)                                          \
            m = MF(w1f0[kt], ld16(pHY, kt * 64), m);                            \
        f32x4 y;                                                                \
        _Pragma("unroll")                                                       \
        for (int e = 0; e < 4; ++e) {                                           \
            float x = m[e] + b1_0v[e];                                          \
            y[e] = x / (1.f + __expf(-x));                                      \
        }                                                                       \
        *(unsigned long long*)(lds + S1_OFF + eoffV) = pk4(y);                  \
    }                                                                           \
    if (XV) {                                                                   \
        f32x4 m = zero4();                                                      \
        _Pragma("unroll")                                                       \
        for (int kt = 0; kt < 8; ++kt)                                          \
            m = MF(w1f1[kt], ld16(pHX, kt * 64), m);                            \
        float p = 0.f;                                                          \
        _Pragma("unroll")                                                       \
        for (int e = 0; e < 4; ++e) {                                           \
            float x = m[e] + b1_1v[e];                                          \
            p += (x / (1.f + __expf(-x))) * wfv[e];                             \
        }                                                                       \
        p += __shfl_xor(p, 16);                                                 \
        p += __shfl_xor(p, 32);                                                 \
        if (lane < 16)                                                          \
            *((float*)(lds + RED_OFF) + (wv << 4) + lane) = p;                  \
    }                                                                           \
    if (ZV) {                                                                   \
        _Pragma("unroll")                                                       \
        for (int j = 0; j < 3; ++j)                                             \
            *(unsigned long long*)(baseX + vstoff[j]) = pk4(vld[j]);            \
    }                                                                           \
    __syncthreads();                                                            \
    if (YV) {                                                                   \
        f32x4 sg = zero4(), ssa = zero4();                                      \
        _Pragma("unroll")                                                       \
        for (int kt = 0; kt < 4; ++kt) {                                        \
            bf16x8 a = ld16(pS1, kt * 64);                                      \
            sg  = MF(w2g0[kt], a, sg);                                          \
            ssa = MF(w2s0[kt], a, ssa);                                         \
        }                                                                       \
        f32x4 g, ssv;                                                           \
        _Pragma("unroll")                                                       \
        for (int e = 0; e < 4; ++e) {                                           \
            g[e]   = sg[e] + b2g0v[e];                                          \
            ssv[e] = ssa[e] + b2s0v[e];                                         \
        }                                                                       \
        *(unsigned long long*)(baseY + VSET + eoffH) = pk4(g);                  \
        _Pragma("unroll")                                                       \
        for (int d = 0; d < 3; ++d) {                                           \
            f32x4 vp;                                                           \
            _Pragma("unroll")                                                   \
            for (int e = 0; e < 4; ++e) vp[e] = v1a[d][e] * ssv[e];             \
            *(unsigned long long*)(baseY + d * 6144 + eoffV) = pk4(vp);         \
        }                                                                       \
    }                                                                           \
    if (ZV)                                                                     \
        *(unsigned long long*)(baseX + VSET + sstoff) = pk4(sld);               \
    if ((XV) && tid < 16) {                                                     \
        float s = 0.f;                                                          \
        _Pragma("unroll")                                                       \
        for (int w = 0; w < 8; ++w) s += *((float*)(lds + RED_OFF) + (w << 4) + tid); \
        sOut[((ty_ - stride) << 4) + tid] = s + cf;                             \
    }                                                                           \
    __syncthreads();                                                            \
}

__global__ __launch_bounds__(512, 2) void eqsc_main(
    const float* __restrict__ S, const float* __restrict__ V,
    const float* __restrict__ u0w, const float* __restrict__ v0w,
    const float* __restrict__ a0w1, const float* __restrict__ a0b1,
    const float* __restrict__ a0w2, const float* __restrict__ a0b2,
    const float* __restrict__ v1w,
    const float* __restrict__ a1w1, const float* __restrict__ a1b1,
    const float* __restrict__ a1w2, const float* __restrict__ a1b2,
    const float* __restrict__ outw, const float* __restrict__ outbp,
    float* __restrict__ sOut, int NT)
{
    __shared__ __align__(16) unsigned char lds[LDS_BYTES];
    const int tid  = threadIdx.x;
    const int lane = tid & 63;
    const int wv   = tid >> 6;
    const int l15  = lane & 15;
    const int lg   = lane >> 4;
    const int grow = wv * 16 + l15;
    const int fb0  = wv * 16 + (lg << 2);

    // lane-invariant address pieces
    const int lgsw    = (lg + (l15 & 7)) << 4;
    const int lrow384 = l15 * 384 + lgsw;
    const int lrow640 = l15 * 640 + lgsw;
    const int erot    = (fb0 << 1) + ((l15 & 7) << 4);
    const int eoffV   = l15 * 384 + erot;
    const int eoffH   = l15 * 640 + erot;

    int vstoff[3], sstoff;
#pragma unroll
    for (int j = 0; j < 3; ++j) {
        int c = tid + (j << 9);
        int d = c >> 9, rem = c & 511;
        int row = rem >> 5, c4 = rem & 31;
        vstoff[j] = d * 6144 + row * 384 + (c4 << 3) + ((row & 7) << 4);
    }
    { int row = tid >> 5, c4 = tid & 31;
      sstoff = row * 640 + (c4 << 3) + ((row & 7) << 4); }

    // ---- folded readout (vector) ----
    f32x4 wfv = zero4();
    float cf = 0.f;
    for (int g = 0; g < 128; ++g) {
        float og = outw[g];
        f32x4 w4 = *(const f32x4*)(a1w2 + g * 128 + fb0);
#pragma unroll
        for (int e = 0; e < 4; ++e) wfv[e] += w4[e] * og;
        cf += a1b2[g] * og;
    }
    cf += outbp[0];

    // ---- persistent weight fragments (bf16): 144 regs ----
    bf16x8 uw0f[4], vw0f[4], w2g0[4], w2s0[4], vw1f[4];
    bf16x8 w1f0[8], w1f1[8];
#pragma unroll
    for (int kt = 0; kt < 4; ++kt) {
        int k0 = kt * 32 + lg * 8;
        uw0f[kt] = bfrag_g(u0w, 128, grow, k0);
        vw0f[kt] = bfrag_g(v0w, 128, grow, k0);
        w2g0[kt] = bfrag_g(a0w2, 128, grow, k0);
        w2s0[kt] = bfrag_g(a0w2, 128, 128 + grow, k0);
        vw1f[kt] = bfrag_g(v1w, 128, grow, k0);
    }
#pragma unroll
    for (int kt = 0; kt < 8; ++kt) {
        int k0 = kt * 32 + lg * 8;
        w1f0[kt] = bfrag_g(a0w1, 256, grow, k0);
        w1f1[kt] = bfrag_g(a1w1, 256, grow, k0);
    }
    const f32x4 b1_0v = *(const f32x4*)(a0b1 + fb0);
    const f32x4 b2g0v = *(const f32x4*)(a0b2 + fb0);
    const f32x4 b2s0v = *(const f32x4*)(a0b2 + 128 + fb0);
    const f32x4 b1_1v = *(const f32x4*)(a1b1 + fb0);

    const int stride = gridDim.x;
    const int t0 = blockIdx.x;
    const int NI = (NT > t0) ? ((NT - t0 + stride - 1) / stride) : 0;

    // ---- prologue: stage tile t0 into set 0 ----
    if (NI > 0) {
        f32x4 vld[3], sld;
#pragma unroll
        for (int j = 0; j < 3; ++j) {
            int c = tid + (j << 9);
            int d = c >> 9, rem = c & 511;
            int row = rem >> 5, c4 = rem & 31;
            vld[j] = *(const f32x4*)(V + (((size_t)((t0 << 4) + row) * 3 + d) << 7) + (c4 << 2));
        }
        { int row = tid >> 5, c4 = tid & 31;
          sld = *(const f32x4*)(S + (((size_t)((t0 << 4) + row)) << 7) + (c4 << 2)); }
#pragma unroll
        for (int j = 0; j < 3; ++j)
            *(unsigned long long*)(lds + vstoff[j]) = pk4(vld[j]);
        *(unsigned long long*)(lds + VSET + sstoff) = pk4(sld);
    }
    __syncthreads();

    // ---- i = 0 (boundary) ----
    EQ_ITER(0, (0 < NI), false, (1 < NI));
    // ---- steady loop: all guards compile-time true, branch-free body ----
    for (int i = 1; i + 1 < NI; ++i)
        EQ_ITER(i, true, true, true);
    // ---- tail boundaries ----
    for (int i = (NI - 1 > 1 ? NI - 1 : 1); i <= NI; ++i)
        EQ_ITER(i, (i < NI), ((i >= 1) && (i - 1 < NI)), (i + 1 < NI));
}

// Dense masked pooling: y[b] = sum_a batch[b,a] * s_out[a]
__global__ __launch_bounds__(256) void eqsc_pool(const float* __restrict__ batch,
                                                 const float* __restrict__ s,
                                                 float* __restrict__ out,
                                                 int NA, int B, int CH)
{
    int b  = blockIdx.x % B;
    int ch = blockIdx.x / B;
    int a0 = ch * CH;
    int a1 = min(a0 + CH, NA);
    const float* br = batch + (size_t)b * NA;
    float acc = 0.f;
    for (int a = a0 + (threadIdx.x << 2); a < a1; a += 256 * 4) {
        f32x4 bb = *(const f32x4*)(br + a);
        f32x4 sv = *(const f32x4*)(s + a);
        acc += bb[0] * sv[0] + bb[1] * sv[1] + bb[2] * sv[2] + bb[3] * sv[3];
    }
#pragma unroll
    for (int off = 32; off > 0; off >>= 1) acc += __shfl_down(acc, off);
    __shared__ float wsum[4];
    if ((threadIdx.x & 63) == 0) wsum[threadIdx.x >> 6] = acc;
    __syncthreads();
    if (threadIdx.x == 0) atomicAdd(&out[b], wsum[0] + wsum[1] + wsum[2] + wsum[3]);
}

extern "C" void kernel_launch(void* const* d_in, const int* in_sizes, int n_in,
                              void* d_out, int out_size, void* d_ws, size_t ws_size,
                              hipStream_t stream)
{
    const float* S     = (const float*)d_in[0];
    const float* V     = (const float*)d_in[1];
    // d_in[2] = pos, unused by the reference
    const float* batch = (const float*)d_in[3];
    const float* u0w   = (const float*)d_in[4];
    const float* v0w   = (const float*)d_in[5];
    const float* a0w1  = (const float*)d_in[6];
    const float* a0b1  = (const float*)d_in[7];
    const float* a0w2  = (const float*)d_in[8];
    const float* a0b2  = (const float*)d_in[9];
    // d_in[10] = u1w: dead code (layer-1 v1 never reaches the scalar output)
    const float* v1w   = (const float*)d_in[11];
    const float* a1w1  = (const float*)d_in[12];
    const float* a1b1  = (const float*)d_in[13];
    const float* a1w2  = (const float*)d_in[14];
    const float* a1b2  = (const float*)d_in[15];
    const float* outw  = (const float*)d_in[16];
    const float* outb  = (const float*)d_in[17];

    const int NA = in_sizes[0] / 128;
    const int NT = NA / 16;                  // 16 atoms per tile
    const int B  = in_sizes[3] / NA;
    float* sAtom = (float*)d_ws;

    hipMemsetAsync(d_out, 0, (size_t)out_size * sizeof(float), stream);

    eqsc_main<<<256, 512, 0, stream>>>(S, V, u0w, v0w, a0w1, a0b1, a0w2, a0b2,
                                       v1w, a1w1, a1b1, a1w2, a1b2,
                                       outw, outb, sAtom, NT);

    const int CH  = 16384;
    const int NCH = (NA + CH - 1) / CH;
    eqsc_pool<<<B * NCH, 256, 0, stream>>>(batch, sAtom, (float*)d_out, NA, B, CH);
}